// Round 5
// baseline (33.821 us; speedup 1.0000x reference)
//
#include <hip/hip_runtime.h>
#include <math.h>

#define H_DIM 2048
#define NUM_V 32
#define DK 128
#define DV 128
#define KSZ 4
#define KEY_DIM 2048
#define VALUE_DIM 4096
#define CONV_DIM 8192

// workspace layout (floats):
#define WS_QKV   0       // 8192
#define WS_Z     8192    // 4096
#define WS_B     12288   // 32
#define WS_A     12320   // 32
#define WS_XN    12352   // 4096 (normed core, pre-gate)

__device__ __forceinline__ float wave_reduce_sum(float v) {
#pragma unroll
    for (int off = 32; off > 0; off >>= 1) v += __shfl_down(v, off, 64);
    return v;
}

// ---- Kernel A: qkv + b + a projections (8256 rows of length 2048) ----
__global__ void proj_kernel(const float* __restrict__ h,
                            const float* __restrict__ qkv_w,
                            const float* __restrict__ b_w,
                            const float* __restrict__ a_w,
                            float* __restrict__ ws) {
    const int R = CONV_DIM + 2 * NUM_V;  // 8256
    int wave = (blockIdx.x * blockDim.x + threadIdx.x) >> 6;
    int lane = threadIdx.x & 63;
    if (wave >= R) return;

    const float* row;
    float* dst;
    if (wave < CONV_DIM) {
        row = qkv_w + (size_t)wave * H_DIM;
        dst = ws + WS_QKV + wave;
    } else if (wave < CONV_DIM + NUM_V) {
        int r = wave - CONV_DIM;
        row = b_w + (size_t)r * H_DIM;
        dst = ws + WS_B + r;
    } else {
        int r = wave - CONV_DIM - NUM_V;
        row = a_w + (size_t)r * H_DIM;
        dst = ws + WS_A + r;
    }

    const float4* row4 = (const float4*)row;
    const float4* h4 = (const float4*)h;
    float acc = 0.f;
#pragma unroll
    for (int i = 0; i < 8; ++i) {
        float4 w4 = row4[lane + 64 * i];
        float4 hv = h4[lane + 64 * i];
        acc += w4.x * hv.x + w4.y * hv.y + w4.z * hv.z + w4.w * hv.w;
    }
    acc = wave_reduce_sum(acc);
    if (lane == 0) *dst = acc;
}

// ---- Kernel B: blocks 0..31 = fused conv+delta-rule+RMSNorm (one per head);
//                blocks 32..543 = z projection (4096 rows) ----
__global__ __launch_bounds__(256) void mid_kernel(
        const float* __restrict__ h,
        const float* __restrict__ conv_state,
        const float* __restrict__ conv_w,
        const float* __restrict__ z_w,
        float* __restrict__ ws,
        const float* __restrict__ rec_in,
        const float* __restrict__ dt_bias,
        const float* __restrict__ A_log,
        const float* __restrict__ norm_w,
        float* __restrict__ new_conv_state,
        float* __restrict__ rec_out) {
    const int t = threadIdx.x;
    const int lane = t & 63;
    const int w = t >> 6;

    if (blockIdx.x >= 32) {
        // ---------------- z projection ----------------
        int zb = blockIdx.x - 32;
        const float4* h4 = (const float4*)h;
#pragma unroll
        for (int rr = 0; rr < 2; ++rr) {
            int r = zb * 4 + w + rr * 2048;
            const float4* r4 = (const float4*)(z_w + (size_t)r * H_DIM);
            float acc = 0.f;
#pragma unroll
            for (int i = 0; i < 8; ++i) {
                float4 w4 = r4[lane + 64 * i];
                float4 hv = h4[lane + 64 * i];
                acc += w4.x * hv.x + w4.y * hv.y + w4.z * hv.z + w4.w * hv.w;
            }
            acc = wave_reduce_sum(acc);
            if (lane == 0) ws[WS_Z + r] = acc;
        }
        return;
    }

    // ---------------- head update ----------------
    __shared__ float qc[DK], kc[DK], vc[DV], dl[DV];
    __shared__ float part[8][DV];
    __shared__ float red[4];

    const int n = blockIdx.x;
    const int sh = n >> 1;   // shared q/k head (VPK=2)

    // fused causal-conv + silu for this head's q/k/v slices
    for (int idx = t; idx < 384; idx += 256) {
        int slice = idx >> 7;   // 0=q,1=k,2=v
        int j = idx & 127;
        int c;
        if (slice == 0)      c = sh * DK + j;
        else if (slice == 1) c = KEY_DIM + sh * DK + j;
        else                 c = 2 * KEY_DIM + n * DV + j;
        float4 cs = ((const float4*)conv_state)[c];
        float4 cw = ((const float4*)conv_w)[c];
        float mq = ws[WS_QKV + c];
        float pre = cs.y * cw.x + cs.z * cw.y + cs.w * cw.z + mq * cw.w;
        float so = pre / (1.f + expf(-pre));   // silu
        if (slice == 0)      qc[j] = so;
        else if (slice == 1) kc[j] = so;
        else                 vc[j] = so;
        float4 ns; ns.x = cs.y; ns.y = cs.z; ns.z = cs.w; ns.w = mq;
        ((float4*)new_conv_state)[c] = ns;   // q/k double-written identically by paired blocks
    }
    __syncthreads();

    // l2-norms of q and k (wave0 -> q, wave1 -> k)
    if (t < 64) {
        float s = qc[t] * qc[t] + qc[t + 64] * qc[t + 64];
        s = wave_reduce_sum(s);
        if (lane == 0) red[0] = s;
    } else if (t < 128) {
        int j = t - 64;
        float s = kc[j] * kc[j] + kc[j + 64] * kc[j + 64];
        s = wave_reduce_sum(s);
        if (lane == 0) red[1] = s;
    }
    __syncthreads();
    if (t < 128) {
        float qin = rsqrtf(red[0] + 1e-6f) * 0.08838834764831845f; // 1/sqrt(128)
        float kin = rsqrtf(red[1] + 1e-6f);
        qc[t] *= qin;
        kc[t] *= kin;
    }

    // per-head scalars
    float bb = ws[WS_B + n];
    float aa = ws[WS_A + n];
    float beta = 1.f / (1.f + expf(-bb));
    float xx = aa + dt_bias[n];
    float sp = (xx > 20.f) ? xx : log1pf(expf(xx));
    float gexp = expf(-expf(A_log[n]) * sp);
    __syncthreads();

    const float4* rn4 = (const float4*)(rec_in + (size_t)n * DK * DV);
    float4* ro4 = (float4*)(rec_out + (size_t)n * DK * DV);
    const int cgp = t & 31;   // float4 column group (0..31)
    const int chp = t >> 5;   // k-chunk (0..7), 16 k each

    // pass 1: kv_mem
    {
        float4 kv = {0.f, 0.f, 0.f, 0.f};
#pragma unroll
        for (int j = 0; j < 16; ++j) {
            int k = chp * 16 + j;
            float4 r = rn4[k * 32 + cgp];
            float kk = kc[k];
            kv.x += r.x * kk; kv.y += r.y * kk; kv.z += r.z * kk; kv.w += r.w * kk;
        }
        ((float4*)part[chp])[cgp] = kv;
    }
    __syncthreads();
    if (t < DV) {
        float s = 0.f;
#pragma unroll
        for (int c = 0; c < 8; ++c) s += part[c][t];
        s *= gexp;
        dl[t] = (vc[t] - s) * beta;
    }
    __syncthreads();

    // pass 2: rec' = rec*gexp + k (x) delta ; core = rec'^T q
    {
        float4 d4 = ((const float4*)dl)[cgp];
        float4 core = {0.f, 0.f, 0.f, 0.f};
#pragma unroll
        for (int j = 0; j < 16; ++j) {
            int k = chp * 16 + j;
            float4 r = rn4[k * 32 + cgp];
            float kk = kc[k];
            float qq = qc[k];
            float4 val;
            val.x = r.x * gexp + kk * d4.x;
            val.y = r.y * gexp + kk * d4.y;
            val.z = r.z * gexp + kk * d4.z;
            val.w = r.w * gexp + kk * d4.w;
            ro4[k * 32 + cgp] = val;
            core.x += val.x * qq; core.y += val.y * qq;
            core.z += val.z * qq; core.w += val.w * qq;
        }
        ((float4*)part[chp])[cgp] = core;
    }
    __syncthreads();
    if (t < DV) {
        float c = 0.f;
#pragma unroll
        for (int cc = 0; cc < 8; ++cc) c += part[cc][t];
        float s = wave_reduce_sum(c * c);
        if (lane == 0) red[2 + (t >> 6)] = s;
        vc[t] = c;   // stash core
    }
    __syncthreads();
    if (t < DV) {
        float c = vc[t];
        float var = (red[2] + red[3]) * (1.f / DV);
        ws[WS_XN + n * DV + t] = c * rsqrtf(var + 1e-6f) * norm_w[t];
    }
}

// ---- Kernel C: gate + output projection (2048 rows of length 4096) ----
__global__ __launch_bounds__(256) void outproj_kernel(
        const float* __restrict__ ws,
        const float* __restrict__ out_proj_w,
        float* __restrict__ hidden_out) {
    __shared__ float4 out_lds[VALUE_DIM / 4];   // 16 KB

    const int t = threadIdx.x;
    const int lane = t & 63;
    const int w = t >> 6;

    // gate: out = xn * silu(z), computed once per block into LDS
    const float4* xn4 = (const float4*)(ws + WS_XN);
    const float4* z4 = (const float4*)(ws + WS_Z);
    for (int i = t; i < VALUE_DIM / 4; i += 256) {
        float4 x = xn4[i];
        float4 z = z4[i];
        float4 o;
        o.x = x.x * (z.x / (1.f + expf(-z.x)));
        o.y = x.y * (z.y / (1.f + expf(-z.y)));
        o.z = x.z * (z.z / (1.f + expf(-z.z)));
        o.w = x.w * (z.w / (1.f + expf(-z.w)));
        out_lds[i] = o;
    }
    __syncthreads();

    // wave per row
    const int row = blockIdx.x * 4 + w;   // 0..2047
    const float4* r4 = (const float4*)(out_proj_w + (size_t)row * VALUE_DIM);
    float acc = 0.f;
#pragma unroll
    for (int i = 0; i < 16; ++i) {
        float4 w4 = r4[lane + 64 * i];
        float4 ov = out_lds[lane + 64 * i];
        acc += w4.x * ov.x + w4.y * ov.y + w4.z * ov.z + w4.w * ov.w;
    }
    acc = wave_reduce_sum(acc);
    if (lane == 0) hidden_out[row] = acc;
}

extern "C" void kernel_launch(void* const* d_in, const int* in_sizes, int n_in,
                              void* d_out, int out_size, void* d_ws, size_t ws_size,
                              hipStream_t stream) {
    const float* h          = (const float*)d_in[0];   // (1,1,2048)
    const float* conv_state = (const float*)d_in[1];   // (1,8192,4)
    const float* rec_in     = (const float*)d_in[2];   // (1,32,128,128)
    const float* conv_w     = (const float*)d_in[3];   // (8192,4)
    const float* qkv_w      = (const float*)d_in[4];   // (8192,2048)
    const float* z_w        = (const float*)d_in[5];   // (4096,2048)
    const float* b_w        = (const float*)d_in[6];   // (32,2048)
    const float* a_w        = (const float*)d_in[7];   // (32,2048)
    const float* out_proj_w = (const float*)d_in[8];   // (2048,4096)
    const float* dt_bias    = (const float*)d_in[9];   // (32,)
    const float* A_log      = (const float*)d_in[10];  // (32,)
    const float* norm_w     = (const float*)d_in[11];  // (128,)

    float* out = (float*)d_out;
    float* hidden_out = out;                           // 2048
    float* new_conv   = out + H_DIM;                   // 32768
    float* rec_out    = out + H_DIM + CONV_DIM * KSZ;  // 524288
    float* ws = (float*)d_ws;

    // A) qkv + b + a projections: 8256 rows, 4 waves/block
    proj_kernel<<<2064, 256, 0, stream>>>(h, qkv_w, b_w, a_w, ws);
    // B) head update (blocks 0..31) || z projection (blocks 32..543)
    mid_kernel<<<544, 256, 0, stream>>>(h, conv_state, conv_w, z_w, ws, rec_in,
                                        dt_bias, A_log, norm_w, new_conv, rec_out);
    // C) gate + output projection
    outproj_kernel<<<512, 256, 0, stream>>>(ws, out_proj_w, hidden_out);
}